// Round 9
// baseline (62.924 us; speedup 1.0000x reference)
//
#include <hip/hip_runtime.h>

// CTC batch cost, B=256, T=512, C=100 (blank=99), U=32, S=2U+1=65.
// Round-5 verified log-domain meet-in-the-middle kernel (absmax 0.0),
// re-packed for TLP: each block handles NB_=8 batch elements with 16 waves
// (1024 threads) -> 4 waves per SIMD co-resident, hiding the serial LSE
// chain's dependency stalls. Grid = B/NB = 32 blocks.
// Wave role: slot = wid>>1 (batch within block), role = wid&1
//   role 0: forward alpha over rows 1..m      (m = (ilen-1)>>1)
//   role 1: backward beta over rows ilen-1..m+1
// ll = LSE_j(alpha_m[j] + beta_m[j]); out = -ln2 * ll.

#define B_ 256
#define T_ 512
#define C_ 100
#define U_ 32
#define BLANK_ 99
#define NEG_ (-1e30f)
#define NB_ 8     // batch elements per block

__device__ __forceinline__ float dpp_shr1(float old_, float src) {  // lane i <- i-1; lane0 <- old
    int r = __builtin_amdgcn_update_dpp(__float_as_int(old_), __float_as_int(src),
                                        0x138, 0xF, 0xF, false);
    return __int_as_float(r);
}
__device__ __forceinline__ float dpp_shl1(float old_, float src) {  // lane i <- i+1; lane63 <- old
    int r = __builtin_amdgcn_update_dpp(__float_as_int(old_), __float_as_int(src),
                                        0x130, 0xF, 0xF, false);
    return __int_as_float(r);
}
__device__ __forceinline__ float bcast_lane(float v, int lane) {
    return __int_as_float(__builtin_amdgcn_readlane(__float_as_int(v), lane));
}

// Issue 32 gather loads, rows TB, TB+1, ... (forward) into bank RV.
#define ISSUE_F(RV, TB)                                                        \
    _Pragma("unroll")                                                          \
    for (int j = 0; j < 32; ++j) {                                             \
        const float* ga = p + (size_t)((TB) + j) * C_;                         \
        asm volatile("global_load_dword %0, %1, off" : "=v"(RV[j]) : "v"(ga)); \
    }
// Issue 32 gather loads, rows TB, TB-1, ... (backward) into bank RV.
#define ISSUE_B(RV, TB)                                                        \
    _Pragma("unroll")                                                          \
    for (int j = 0; j < 32; ++j) {                                             \
        const float* ga = p + (size_t)((TB) - j) * C_;                         \
        asm volatile("global_load_dword %0, %1, off" : "=v"(RV[j]) : "v"(ga)); \
    }

#define WAIT_BANK()                                                            \
    asm volatile("s_waitcnt vmcnt(32)" ::: "memory");                          \
    __builtin_amdgcn_sched_barrier(0);

// Forward DP step consuming row T_IDX (raw prob RV); freeze when T_IDX > m.
#define FSTEP(RV, T_IDX)                                                       \
    {                                                                          \
        float e   = __builtin_amdgcn_logf((RV) + 1e-7f);                       \
        float eb  = bcast_lane(e, 1);            /* lane1 = state2 = blank */  \
        float up1 = dpp_shr1(a00, a0);                                         \
        float up2 = dpp_shr1(NEG_, up1);                                       \
        up2 = canskip ? up2 : NEG_;                                            \
        float mx  = fmaxf(fmaxf(a0, up1), up2);                                \
        float sum = __builtin_amdgcn_exp2f(a0  - mx)                           \
                  + __builtin_amdgcn_exp2f(up1 - mx)                           \
                  + __builtin_amdgcn_exp2f(up2 - mx);                          \
        float na  = (mx + e) + __builtin_amdgcn_logf(sum);                     \
        const bool upd = ((T_IDX) <= m);                                       \
        a0  = upd ? na         : a0;                                           \
        a00 = upd ? (a00 + eb) : a00;                                          \
    }

// Backward DP step, step index K (consumes row ilen-1-K); freeze when K >= nb.
#define BSTEP(RV, K)                                                           \
    {                                                                          \
        float e   = __builtin_amdgcn_logf((RV) + 1e-7f);                       \
        float e64 = bcast_lane(e, 0);            /* lane0 = state0 = blank */  \
        float g   = b0 + e;                                                    \
        float g64 = b64 + e64;                                                 \
        float g1  = dpp_shl1(g64, g);            /* lane j <- g[j+1] */        \
        float g2  = dpp_shl1(NEG_, g1);          /* lane j <- g[j+2] */        \
        g2 = csb ? g2 : NEG_;                                                  \
        float mx  = fmaxf(fmaxf(g, g1), g2);                                   \
        float sum = __builtin_amdgcn_exp2f(g  - mx)                            \
                  + __builtin_amdgcn_exp2f(g1 - mx)                            \
                  + __builtin_amdgcn_exp2f(g2 - mx);                           \
        float nbv = mx + __builtin_amdgcn_logf(sum);                           \
        const bool upd = ((K) < nb);                                           \
        b0  = upd ? nbv : b0;                                                  \
        b64 = upd ? g64 : b64;                                                 \
    }

__global__ __launch_bounds__(1024, 1) void ctc_fwd_kernel(
    const float* __restrict__ y_pred,
    const int*   __restrict__ labels,
    const int*   __restrict__ input_length,
    const int*   __restrict__ label_length,
    float*       __restrict__ out)
{
    const int lane = threadIdx.x & 63;
    const int wid  = threadIdx.x >> 6;
    const int slot = wid >> 1;                 // batch element within block
    const int role = wid & 1;                  // 0 = forward, 1 = backward
    const int b    = blockIdx.x * NB_ + slot;

    const int ilen = min(input_length[b], T_);
    const int llen = label_length[b];
    const int m    = (ilen - 1) >> 1;          // forward computes alpha_m
    const int nb   = ilen - 1 - m;             // backward steps
    const int last = 2 * llen;

    const int* lab = labels + b * U_;

    __shared__ float af[NB_][66];
    __shared__ float bf[NB_][66];

    float rvA[32], rvB[32];

    if (role == 0) {
        // ================ forward: alpha over rows 0..m ================
        const int s = lane + 1;
        int  cls;  bool canskip;
        if (s & 1) {
            const int k = s >> 1;
            cls = lab[k];
            const int prev = (k > 0) ? lab[k - 1] : -1;
            canskip = (s >= 3) && (cls != prev);
        } else { cls = BLANK_; canskip = false; }

        const float* p = y_pred + ((size_t)b * T_) * C_ + cls;

        float e0  = __builtin_amdgcn_logf(p[0] + 1e-7f);
        float a0  = (lane == 0) ? e0 : NEG_;
        float a00 = bcast_lane(e0, 1);

        ISSUE_F(rvA, 1)
        #pragma unroll 1
        for (int i = 0; i < 4; ++i) {
            const int tA = 1 + i * 64;
            ISSUE_F(rvB, tA + 32)
            WAIT_BANK()
            #pragma unroll
            for (int j = 0; j < 32; ++j) FSTEP(rvA[j], tA + j)
            ISSUE_F(rvA, tA + 64)
            WAIT_BANK()
            #pragma unroll
            for (int j = 0; j < 32; ++j) FSTEP(rvB[j], tA + 32 + j)
        }
        asm volatile("s_waitcnt vmcnt(0)" ::: "memory");

        af[slot][lane + 1] = a0;
        if (lane == 0) af[slot][0] = a00;
    } else {
        // ================ backward: beta over rows ilen-1..m+1 ================
        const int st = lane;
        int cls;
        if (st & 1) cls = lab[st >> 1]; else cls = BLANK_;
        bool csb = false;
        if ((st & 1) && st <= 61) {
            const int k2 = (st + 2) >> 1;
            csb = (lab[k2] != lab[k2 - 1]);
        }

        const float* p = y_pred + ((size_t)b * T_) * C_ + cls;

        float b0  = (st == last || st == last - 1) ? 0.0f : NEG_;
        float b64 = (last == 64) ? 0.0f : NEG_;

        const int t0 = ilen - 1;
        ISSUE_B(rvA, t0)
        #pragma unroll 1
        for (int i = 0; i < 4; ++i) {
            const int k0 = i * 64;
            ISSUE_B(rvB, t0 - (k0 + 32))
            WAIT_BANK()
            #pragma unroll
            for (int j = 0; j < 32; ++j) BSTEP(rvA[j], k0 + j)
            ISSUE_B(rvA, t0 - (k0 + 64))
            WAIT_BANK()
            #pragma unroll
            for (int j = 0; j < 32; ++j) BSTEP(rvB[j], k0 + 32 + j)
        }
        asm volatile("s_waitcnt vmcnt(0)" ::: "memory");

        bf[slot][lane] = b0;
        if (lane == 0) bf[slot][64] = b64;
    }

    __syncthreads();

    if (role == 0) {
        // ll = LSE_{j=0..64}(alpha_m[j] + beta_m[j])
        float x   = af[slot][lane] + bf[slot][lane];
        float x64 = af[slot][64] + bf[slot][64];
        float M = x;
        #pragma unroll
        for (int off = 1; off < 64; off <<= 1) M = fmaxf(M, __shfl_xor(M, off));
        M = fmaxf(M, x64);
        float sm = __builtin_amdgcn_exp2f(x - M);
        #pragma unroll
        for (int off = 1; off < 64; off <<= 1) sm += __shfl_xor(sm, off);
        sm += __builtin_amdgcn_exp2f(x64 - M);
        float ll = M + __builtin_amdgcn_logf(sm);
        if (lane == 0) out[b] = -0.69314718055994530942f * ll;
    }
}

extern "C" void kernel_launch(void* const* d_in, const int* in_sizes, int n_in,
                              void* d_out, int out_size, void* d_ws, size_t ws_size,
                              hipStream_t stream) {
    const float* y_pred       = (const float*)d_in[0];
    const int*   labels       = (const int*)d_in[1];
    const int*   input_length = (const int*)d_in[2];
    const int*   label_length = (const int*)d_in[3];
    float*       out          = (float*)d_out;

    hipLaunchKernelGGL(ctc_fwd_kernel, dim3(B_ / NB_), dim3(NB_ * 128), 0, stream,
                       y_pred, labels, input_length, label_length, out);
}

// Round 12
// 31.206 us; speedup vs baseline: 2.0164x; 2.0164x over previous
//
#include <hip/hip_runtime.h>

// CTC batch cost, B=256, T=512, C=100 (blank=99), U=32, S=2U+1=65.
// Verified round-5 MITM structure (256 blocks x 128 thr): wave0 = forward
// alpha to row m (m EVEN, m = (ilen>>1)&~1), wave1 = backward beta down to
// row m; ll = LSE_j(alpha_m[j]+beta_m[j]).  NEW: 2-STEP-FUSED log-domain DP.
// Composed 5-tap weights W[k]/V[k] depend only on emissions -> computed
// off-chain; serial transcendental depth per original step halves (2 -> 1).
// Emission-only combos use linear adds + one log2 (safe: no accumulation).
// Backward odd step count handled by one block-uniform 1-step pre-step.
// Loads: inline-asm double-banked global_load_dword, counted vmcnt(32).

#define B_ 256
#define T_ 512
#define C_ 100
#define U_ 32
#define BLANK_ 99
#define NEG_  (-1e30f)
#define NINF_ (-__builtin_inff())

__device__ __forceinline__ float dpp_shr1(float old_, float src) {  // lane i <- i-1; lane0 <- old
    int r = __builtin_amdgcn_update_dpp(__float_as_int(old_), __float_as_int(src),
                                        0x138, 0xF, 0xF, false);
    return __int_as_float(r);
}
__device__ __forceinline__ float dpp_shl1(float old_, float src) {  // lane i <- i+1; lane63 <- old
    int r = __builtin_amdgcn_update_dpp(__float_as_int(old_), __float_as_int(src),
                                        0x130, 0xF, 0xF, false);
    return __int_as_float(r);
}
__device__ __forceinline__ float bcast_lane(float v, int lane) {
    return __int_as_float(__builtin_amdgcn_readlane(__float_as_int(v), lane));
}

#define ISSUE_F(RV, TB)                                                        \
    _Pragma("unroll")                                                          \
    for (int j = 0; j < 32; ++j) {                                             \
        const float* ga = p + (size_t)((TB) + j) * C_;                         \
        asm volatile("global_load_dword %0, %1, off" : "=v"(RV[j]) : "v"(ga)); \
    }
#define ISSUE_B(RV, TB)                                                        \
    _Pragma("unroll")                                                          \
    for (int j = 0; j < 32; ++j) {                                             \
        const float* ga = p + (size_t)((TB) - j) * C_;                         \
        asm volatile("global_load_dword %0, %1, off" : "=v"(RV[j]) : "v"(ga)); \
    }
#define WAIT_BANK()                                                            \
    asm volatile("s_waitcnt vmcnt(32)" ::: "memory");                          \
    __builtin_amdgcn_sched_barrier(0);

// ---- fused 2-step forward: consumes rows T2-1 (RV1) and T2 (RV2) ----------
// taps a[s-k], k=0..4; W[k] from emissions only (off the alpha chain).
#define FSTEP2(RV1, RV2, T2)                                                   \
    {                                                                          \
        float fA  = (RV1) + 1e-7f;                                             \
        float fB  = (RV2) + 1e-7f;                                             \
        float e1  = __builtin_amdgcn_logf(fA);                                 \
        float e2  = __builtin_amdgcn_logf(fB);                                 \
        float eb1 = bcast_lane(e1, 1);                                         \
        float eb2 = bcast_lane(e2, 1);                                         \
        float fb1 = bcast_lane(fA, 1);                                         \
        float fm1 = dpp_shr1(fb1, fA);          /* f1[s-1] */                  \
        float fm2 = dpp_shr1(0.0f, fm1);        /* f1[s-2] */                  \
        float m1l = dpp_shr1(eb1, e1);          /* E1[s-1] */                  \
        float m2l = dpp_shr1(NEG_, m1l);        /* E1[s-2] */                  \
        float W1  = __builtin_amdgcn_logf(fA + fm1);                           \
        float W2  = cs2 ? __builtin_amdgcn_logf(fm1 + fA + fm2) : m1l;         \
        float W3  = cs2 ? m2l : (csm1 ? m1l : NINF_);                          \
        float W4  = cs24 ? m2l : NINF_;                                        \
        float ee  = eb1 + eb2;                                                 \
        float up1 = dpp_shr1(a00, a0);                                         \
        float up2 = dpp_shr1(NEG_, up1);                                       \
        float up3 = dpp_shr1(NEG_, up2);                                       \
        float up4 = dpp_shr1(NEG_, up3);                                       \
        float t0  = a0  + e1;                                                  \
        float t1  = up1 + W1;                                                  \
        float t2v = up2 + W2;                                                  \
        float t3  = up3 + W3;                                                  \
        float t4  = up4 + W4;                                                  \
        float mx  = fmaxf(fmaxf(fmaxf(t0, t1), fmaxf(t2v, t3)), t4);           \
        float sum = __builtin_amdgcn_exp2f(t0  - mx)                           \
                  + __builtin_amdgcn_exp2f(t1  - mx)                           \
                  + __builtin_amdgcn_exp2f(t2v - mx)                           \
                  + __builtin_amdgcn_exp2f(t3  - mx)                           \
                  + __builtin_amdgcn_exp2f(t4  - mx);                          \
        float na  = mx + __builtin_amdgcn_logf(sum) + e2;                      \
        const bool upd = ((T2) <= m);                                          \
        a0  = upd ? na         : a0;                                           \
        a00 = upd ? (a00 + ee) : a00;                                          \
    }

// ---- fused 2-step backward: consumes rows rA (RVA, later) and rA-1 (RVB) --
// taps b[j+k]; V[k] = eAp_k + S_k from emissions only.
#define BSTEP2(RVA, RVB, Q)                                                    \
    {                                                                          \
        float fA   = (RVA) + 1e-7f;                                            \
        float fB   = (RVB) + 1e-7f;                                            \
        float eA   = __builtin_amdgcn_logf(fA);                                \
        float eB   = __builtin_amdgcn_logf(fB);                                \
        float eA0  = bcast_lane(eA, 0);                                        \
        float eB0  = bcast_lane(eB, 0);                                        \
        float l64  = eA0 + eB0;                                                \
        float f64B = bcast_lane(fB, 0);                                        \
        float fBp1 = dpp_shl1(f64B, fB);        /* fB[j+1] */                  \
        float fBp2 = dpp_shl1(0.0f, fBp1);      /* fB[j+2] */                  \
        float eAp1 = dpp_shl1(eA0, eA);         /* EA[j+1] */                  \
        float eAp2 = dpp_shl1(NINF_, eAp1);                                    \
        float eAp3 = dpp_shl1(NINF_, eAp2);                                    \
        float eAp4 = dpp_shl1(NINF_, eAp3);                                    \
        float eBp1 = dpp_shl1(eB0, eB);                                        \
        float eBp2 = dpp_shl1(NINF_, eBp1);                                    \
        float S1   = __builtin_amdgcn_logf(fB + fBp1);                         \
        float S2   = csb ? __builtin_amdgcn_logf(fBp1 + fB + fBp2) : eBp1;     \
        float S3   = csb ? eBp2 : (csb1 ? eBp1 : NINF_);                       \
        float S4   = csb24 ? eBp2 : NINF_;                                     \
        float V0   = eA + eB;                                                  \
        float V1   = eAp1 + S1;                                                \
        float V2   = eAp2 + S2;                                                \
        float V3   = eAp3 + S3;                                                \
        float V4   = eAp4 + S4;                                                \
        float d1   = dpp_shl1(b64, b0);                                        \
        float d2   = dpp_shl1(NEG_, d1);                                       \
        float d3   = dpp_shl1(NEG_, d2);                                       \
        float d4   = dpp_shl1(NEG_, d3);                                       \
        float t0   = b0 + V0;                                                  \
        float t1   = d1 + V1;                                                  \
        float t2v  = d2 + V2;                                                  \
        float t3   = d3 + V3;                                                  \
        float t4   = d4 + V4;                                                  \
        float mx   = fmaxf(fmaxf(fmaxf(t0, t1), fmaxf(t2v, t3)), t4);          \
        float sum  = __builtin_amdgcn_exp2f(t0  - mx)                          \
                   + __builtin_amdgcn_exp2f(t1  - mx)                          \
                   + __builtin_amdgcn_exp2f(t2v - mx)                          \
                   + __builtin_amdgcn_exp2f(t3  - mx)                          \
                   + __builtin_amdgcn_exp2f(t4  - mx);                         \
        float nb0  = mx + __builtin_amdgcn_logf(sum);                          \
        const bool upd = ((Q) < nbh);                                          \
        b0  = upd ? nb0        : b0;                                           \
        b64 = upd ? (b64 + l64): b64;                                          \
    }

__global__ __launch_bounds__(128, 1) void ctc_fwd_kernel(
    const float* __restrict__ y_pred,
    const int*   __restrict__ labels,
    const int*   __restrict__ input_length,
    const int*   __restrict__ label_length,
    float*       __restrict__ out)
{
    const int b    = blockIdx.x;
    const int lane = threadIdx.x & 63;
    const int wid  = threadIdx.x >> 6;

    const int ilen = min(input_length[b], T_);
    const int llen = label_length[b];
    const int m    = (ilen >> 1) & ~1;         // EVEN split row; fwd steps = m <= 256
    const int nb   = ilen - 1 - m;             // backward steps (<= 256)
    const int last = 2 * llen;

    const int* lab = labels + b * U_;

    __shared__ float af[66];
    __shared__ float bf[66];

    float rvA[32], rvB[32];

    if (wid == 0) {
        // ================ forward: alpha over rows 0..m (2-step fused) =====
        const int s = lane + 1;
        int cls;
        if (s & 1) cls = lab[min(s >> 1, U_ - 1)]; else cls = BLANK_;
        // cs[x] = x odd && x>=3 && lab[x>>1] != lab[x>>1 - 1]
        const bool cs2  = (s & 1) && (s >= 3) &&
                          (lab[min(s >> 1, U_ - 1)] != lab[min((s >> 1) - 1, U_ - 1)]);
        const int  sm1  = s - 1;
        const bool csm1 = (sm1 & 1) && (sm1 >= 3) &&
                          (lab[min(sm1 >> 1, U_ - 1)] != lab[min((sm1 >> 1) - 1, U_ - 1)]);
        const int  sm2  = s - 2;
        const bool cs24 = cs2 && (sm2 >= 3) && (sm2 & 1) &&
                          (lab[min(sm2 >> 1, U_ - 1)] != lab[min((sm2 >> 1) - 1, U_ - 1)]);

        const float* p = y_pred + ((size_t)b * T_) * C_ + cls;

        float e0  = __builtin_amdgcn_logf(p[0] + 1e-7f);
        float a0  = (lane == 0) ? e0 : NEG_;
        float a00 = bcast_lane(e0, 1);

        ISSUE_F(rvA, 1)
        #pragma unroll 1
        for (int i = 0; i < 4; ++i) {
            const int tA = 1 + i * 64;
            ISSUE_F(rvB, tA + 32)
            WAIT_BANK()
            #pragma unroll
            for (int j2 = 0; j2 < 16; ++j2)
                FSTEP2(rvA[2 * j2], rvA[2 * j2 + 1], tA + 2 * j2 + 1)
            ISSUE_F(rvA, tA + 64)
            WAIT_BANK()
            #pragma unroll
            for (int j2 = 0; j2 < 16; ++j2)
                FSTEP2(rvB[2 * j2], rvB[2 * j2 + 1], tA + 32 + 2 * j2 + 1)
        }
        asm volatile("s_waitcnt vmcnt(0)" ::: "memory");

        af[lane + 1] = a0;
        if (lane == 0) af[0] = a00;
    } else {
        // ================ backward: beta over rows ilen-1..m (2-step fused) =
        const int st = lane;
        int cls;
        if (st & 1) cls = lab[min(st >> 1, U_ - 1)]; else cls = BLANK_;
        // csb[x] = skip x -> x+2 allowed (x odd, x<=61, labels differ)
        const bool csb   = (st & 1) && (st <= 61) &&
                           (lab[min((st + 2) >> 1, U_ - 1)] != lab[min(((st + 2) >> 1) - 1, U_ - 1)]);
        const int  sp1   = st + 1;
        const bool csb1  = (sp1 & 1) && (sp1 <= 61) &&
                           (lab[min((sp1 + 2) >> 1, U_ - 1)] != lab[min(((sp1 + 2) >> 1) - 1, U_ - 1)]);
        const int  sp2   = st + 2;
        const bool csb24 = csb && (sp2 & 1) && (sp2 <= 61) &&
                           (lab[min((sp2 + 2) >> 1, U_ - 1)] != lab[min(((sp2 + 2) >> 1) - 1, U_ - 1)]);

        const float* p = y_pred + ((size_t)b * T_) * C_ + cls;

        float b0  = (st == last || st == last - 1) ? 0.0f : NEG_;
        float b64 = (last == 64) ? 0.0f : NEG_;

        const int t0   = ilen - 1;
        const int dlt  = nb & 1;               // block-uniform parity
        const int nbh  = nb >> 1;              // fused steps
        const int t0b  = t0 - dlt;             // fused load base

        if (dlt) {                             // single 1-step pre-step (row t0)
            float rpre;
            {
                const float* ga = p + (size_t)t0 * C_;
                asm volatile("global_load_dword %0, %1, off" : "=v"(rpre) : "v"(ga));
            }
            asm volatile("s_waitcnt vmcnt(0)" ::: "memory");
            float e   = __builtin_amdgcn_logf(rpre + 1e-7f);
            float e64 = bcast_lane(e, 0);
            float g   = b0 + e;
            float g64 = b64 + e64;
            float g1  = dpp_shl1(g64, g);
            float g2  = dpp_shl1(NEG_, g1);
            g2 = csb ? g2 : NEG_;
            float mx  = fmaxf(fmaxf(g, g1), g2);
            float sum = __builtin_amdgcn_exp2f(g  - mx)
                      + __builtin_amdgcn_exp2f(g1 - mx)
                      + __builtin_amdgcn_exp2f(g2 - mx);
            b0  = mx + __builtin_amdgcn_logf(sum);
            b64 = g64;
        }

        ISSUE_B(rvA, t0b)
        #pragma unroll 1
        for (int i = 0; i < 4; ++i) {
            const int k0 = i * 64;
            ISSUE_B(rvB, t0b - (k0 + 32))
            WAIT_BANK()
            #pragma unroll
            for (int j2 = 0; j2 < 16; ++j2)
                BSTEP2(rvA[2 * j2], rvA[2 * j2 + 1], i * 32 + j2)
            ISSUE_B(rvA, t0b - (k0 + 64))
            WAIT_BANK()
            #pragma unroll
            for (int j2 = 0; j2 < 16; ++j2)
                BSTEP2(rvB[2 * j2], rvB[2 * j2 + 1], i * 32 + 16 + j2)
        }
        asm volatile("s_waitcnt vmcnt(0)" ::: "memory");

        bf[lane] = b0;
        if (lane == 0) bf[64] = b64;
    }

    __syncthreads();

    if (wid == 0) {
        // ll = LSE_{j=0..64}(alpha_m[j] + beta_m[j])   (round-5 verified)
        float x   = af[lane] + bf[lane];
        float x64 = af[64] + bf[64];
        float M = x;
        #pragma unroll
        for (int off = 1; off < 64; off <<= 1) M = fmaxf(M, __shfl_xor(M, off));
        M = fmaxf(M, x64);
        float sm = __builtin_amdgcn_exp2f(x - M);
        #pragma unroll
        for (int off = 1; off < 64; off <<= 1) sm += __shfl_xor(sm, off);
        sm += __builtin_amdgcn_exp2f(x64 - M);
        float ll = M + __builtin_amdgcn_logf(sm);
        if (lane == 0) out[b] = -0.69314718055994530942f * ll;
    }
}

extern "C" void kernel_launch(void* const* d_in, const int* in_sizes, int n_in,
                              void* d_out, int out_size, void* d_ws, size_t ws_size,
                              hipStream_t stream) {
    const float* y_pred       = (const float*)d_in[0];
    const int*   labels       = (const int*)d_in[1];
    const int*   input_length = (const int*)d_in[2];
    const int*   label_length = (const int*)d_in[3];
    float*       out          = (float*)d_out;

    hipLaunchKernelGGL(ctc_fwd_kernel, dim3(B_), dim3(128), 0, stream,
                       y_pred, labels, input_length, label_length, out);
}